// Round 3
// baseline (25.137 us; speedup 1.0000x reference)
//
#include <hip/hip_runtime.h>

#define BB 512
#define CC 128
#define EPS 1e-6f
#define NPAIR 130816       // 512*511/2
#define PAIRBLK 511        // NPAIR / 256
#define GRID2 512          // PAIRBLK pair-blocks + 1 sim_batch block

__device__ __forceinline__ int tri(int a) { return (a * (1023 - a)) >> 1; }

// ---------------------------------------------------------------------------
// K1: 128 blocks x 256 threads; one wave per row. softmax(predicts/T) and all
// per-row precomputes, all-shuffle (no __syncthreads). Also zeroes the ticket.
//   pxl[b][c] = (p, p*logp)   lg[b][c] = log(p+eps)   lgT[c][b] = lg transposed
//   H[b] = sum_c p*logp       wxw[b] = (p, p*logp) at c=label   lgw[b] = lg at label
//   hits[b] = runner-up class if top1==label else -1
// ---------------------------------------------------------------------------
__global__ __launch_bounds__(256) void row_kernel(
    const float* __restrict__ predicts, const int* __restrict__ labels,
    const float* __restrict__ Tp,
    float2* __restrict__ pxl, float* __restrict__ lg, float* __restrict__ lgT,
    float* __restrict__ H, float2* __restrict__ wxw, float* __restrict__ lgw,
    int* __restrict__ hits, unsigned int* __restrict__ ticket) {
    const int tid = threadIdx.x, lane = tid & 63;
    const int row = blockIdx.x * 4 + (tid >> 6);
    if (blockIdx.x == 0 && tid == 0) *ticket = 0u;

    const float T = Tp[0];
    const float z0 = predicts[row * CC + lane] / T;
    const float z1 = predicts[row * CC + 64 + lane] / T;

    float m = fmaxf(z0, z1);
    for (int s = 32; s; s >>= 1) m = fmaxf(m, __shfl_xor(m, s, 64));
    const float e0 = expf(z0 - m), e1 = expf(z1 - m);
    float sum = e0 + e1;
    for (int s = 32; s; s >>= 1) sum += __shfl_xor(sum, s, 64);

    const float inv = 1.0f / sum, ls = logf(sum);
    const float p0 = e0 * inv, p1 = e1 * inv;
    const float lp0 = (z0 - m) - ls, lp1 = (z1 - m) - ls;  // log p (exact-ish)
    const float lg0 = logf(p0 + EPS), lg1 = logf(p1 + EPS);
    const float x0 = p0 * lp0, x1 = p1 * lp1;

    pxl[row * CC + lane]      = make_float2(p0, x0);
    pxl[row * CC + 64 + lane] = make_float2(p1, x1);
    lg[row * CC + lane]      = lg0;
    lg[row * CC + 64 + lane] = lg1;
    lgT[lane * BB + row]        = lg0;
    lgT[(64 + lane) * BB + row] = lg1;

    float hs = x0 + x1;
    for (int s = 32; s; s >>= 1) hs += __shfl_xor(hs, s, 64);

    const int lbl = labels[row];
    if (lane == 0) H[row] = hs;
    if (lane == (lbl & 63)) {
        const bool hi = lbl >= 64;
        wxw[row] = make_float2(hi ? p1 : p0, hi ? x1 : x0);
        lgw[row] = hi ? lg1 : lg0;
    }

    // stable top-2: key = (float bits << 32) | (127 - idx); p>=0 so bit order
    // == value order; ties -> larger (127-idx) -> smaller idx (argsort(-p)).
    unsigned long long k0 =
        (((unsigned long long)__float_as_uint(p0)) << 32) | (unsigned)(127 - lane);
    unsigned long long k1 =
        (((unsigned long long)__float_as_uint(p1)) << 32) | (unsigned)(127 - (lane + 64));
    unsigned long long hi = k0 > k1 ? k0 : k1;
    unsigned long long lo = k0 > k1 ? k1 : k0;
    for (int s = 32; s; s >>= 1) {
        const unsigned long long ohi = __shfl_xor(hi, s, 64);
        const unsigned long long olo = __shfl_xor(lo, s, 64);
        const unsigned long long nhi = hi > ohi ? hi : ohi;
        const unsigned long long c1 = hi > ohi ? ohi : hi;   // min of the two firsts
        const unsigned long long c2 = lo > olo ? lo : olo;   // max of the two seconds
        lo = c1 > c2 ? c1 : c2;
        hi = nhi;
    }
    if (lane == 0) {
        const int i1 = 127 - (int)(hi & 0xFFFFFFFFu);
        const int i2 = 127 - (int)(lo & 0xFFFFFFFFu);
        hits[row] = (i1 == lbl) ? i2 : -1;
    }
}

// ---------------------------------------------------------------------------
// K2: 512 blocks x 256 threads.
//   blocks 0..510 : one thread per pair (a<b). diff-label: 2-term closed form;
//                   same-label: cooperative wave dot. Per-block double partials.
//   block 511     : zero sim_batch (out+1) and apply the <=512 hit increments.
//   last block (atomic ticket) reduces the 511 partial rows and writes out[0].
// ---------------------------------------------------------------------------
__global__ __launch_bounds__(256) void main_kernel(
    const float2* __restrict__ pxl, const float* __restrict__ lg,
    const float* __restrict__ lgT, const float* __restrict__ H,
    const float2* __restrict__ wxw, const float* __restrict__ lgw,
    const int* __restrict__ labels, const int* __restrict__ hits,
    const float* __restrict__ sim_all, const int* __restrict__ epoch_p,
    const float* __restrict__ mu_p, const float* __restrict__ eta_p,
    double* __restrict__ partials, unsigned int* __restrict__ ticket,
    float* __restrict__ out) {
    const int tid = threadIdx.x, lane = tid & 63, bid = blockIdx.x;
    __shared__ double sred[4][4];
    __shared__ int lastflag;

    if (bid < PAIRBLK) {
        const int k = bid * 256 + tid;  // 0..130815, all valid
        int a = (int)((1023.0 - sqrt(1046529.0 - 8.0 * (double)k)) * 0.5);
        if (a < 0) a = 0;
        while (tri(a + 1) <= k) ++a;
        while (tri(a) > k) --a;
        const int b = a + 1 + (k - tri(a));

        const int la = labels[a], lb = labels[b];
        const bool same = (la == lb);
        double ic = 0.0, isc = 0.0, scnt = 0.0, dcnt = 0.0;

        if (!same) {
            const float2 wa = wxw[a];            // (p[a,la], xlg[a,la]) broadcast-ish
            const float g = lgT[la * BB + b];    // coalesced over b
            const float2 pa = pxl[a * CC + lb];  // in-row gather, L1
            const float t1 = wa.y - wa.x * g;
            const float t2 = pa.y - pa.x * lgw[b];
            const float sim = (epoch_p[0] == 0) ? 1.0f : sim_all[la * CC + lb];
            isc = fabsf((t1 + t2) * sim);
            dcnt = 1.0;
        }

        // cooperative same-label dots: IC term = |H[a] - dot(p[a], lg[b])|
        unsigned long long msk = __ballot(same);
        while (msk) {
            const int src = __builtin_ctzll(msk);
            msk &= msk - 1;
            const int aa = __shfl(a, src, 64);
            const int bb = __shfl(b, src, 64);
            float dot = pxl[aa * CC + lane].x * lg[bb * CC + lane] +
                        pxl[aa * CC + 64 + lane].x * lg[bb * CC + 64 + lane];
            for (int s = 32; s; s >>= 1) dot += __shfl_xor(dot, s, 64);
            if (lane == src) { ic = fabs((double)H[aa] - (double)dot); scnt = 1.0; }
        }

        double vals[4] = {ic, isc, scnt, dcnt};
        #pragma unroll
        for (int q = 0; q < 4; ++q) {
            double v = vals[q];
            for (int s = 32; s; s >>= 1) v += __shfl_xor(v, s, 64);
            if (lane == 0) sred[tid >> 6][q] = v;
        }
        __syncthreads();
        if (tid < 4)
            partials[bid * 4 + tid] =
                sred[0][tid] + sred[1][tid] + sred[2][tid] + sred[3][tid];
    } else {
        // sim_batch block: zero out[1..16384] then apply hits
        float* sb = out + 1;
        #pragma unroll
        for (int i = 0; i < 64; ++i) sb[i * 256 + tid] = 0.0f;
        __syncthreads();  // waitcnt: zeros are in this CU's L2 before the RMWs
        for (int r = tid; r < BB; r += 256) {
            const int h = hits[r];
            if (h >= 0) atomicAdd(&sb[labels[r] * CC + h], 1.0f);
        }
    }

    // ----- ticket: last block to finish reduces partials and finalizes -----
    __syncthreads();
    if (tid == 0) {
        __threadfence();  // release: L2 writeback so partials are device-visible
        const unsigned old = atomicAdd(ticket, 1u);
        lastflag = (old == GRID2 - 1) ? 1 : 0;
    }
    __syncthreads();
    if (lastflag) {
        __threadfence();  // acquire: invalidate so we see all partials
        double v0 = 0, v1 = 0, v2 = 0, v3 = 0;
        for (int i = tid; i < PAIRBLK; i += 256) {
            v0 += partials[i * 4 + 0];
            v1 += partials[i * 4 + 1];
            v2 += partials[i * 4 + 2];
            v3 += partials[i * 4 + 3];
        }
        for (int s = 32; s; s >>= 1) {
            v0 += __shfl_xor(v0, s, 64);
            v1 += __shfl_xor(v1, s, 64);
            v2 += __shfl_xor(v2, s, 64);
            v3 += __shfl_xor(v3, s, 64);
        }
        if (lane == 0) {
            sred[tid >> 6][0] = v0; sred[tid >> 6][1] = v1;
            sred[tid >> 6][2] = v2; sred[tid >> 6][3] = v3;
        }
        __syncthreads();
        if (tid == 0) {
            double IC  = sred[0][0] + sred[1][0] + sred[2][0] + sred[3][0];
            double ISC = sred[0][1] + sred[1][1] + sred[2][1] + sred[3][1];
            const double sc = sred[0][2] + sred[1][2] + sred[2][2] + sred[3][2];
            const double dc = sred[0][3] + sred[1][3] + sred[2][3] + sred[3][3];
            if (sc != 0.0) IC = IC / sc;
            if (dc != 0.0) ISC = ISC / dc;
            if (ISC != 0.0) ISC = (1.0 / (ISC + (double)EPS)) * (double)mu_p[0];
            IC = IC * (double)eta_p[0];
            out[0] = (float)(IC + ISC);
            *ticket = 0u;  // reset for next replay (K1 also re-zeroes)
        }
    }
}

extern "C" void kernel_launch(void* const* d_in, const int* in_sizes, int n_in,
                              void* d_out, int out_size, void* d_ws, size_t ws_size,
                              hipStream_t stream) {
    const float* predicts = (const float*)d_in[0];  // (512,128) f32
    const int*   labels   = (const int*)d_in[1];    // (512,) i32
    const float* sim_all  = (const float*)d_in[2];  // (128,128) f32
    const int*   epoch    = (const int*)d_in[3];    // scalar i32
    const float* T        = (const float*)d_in[4];  // scalar f32
    const float* mu       = (const float*)d_in[5];  // scalar f32
    const float* eta      = (const float*)d_in[6];  // scalar f32

    float* out = (float*)d_out;  // [0]=IC+ISC, [1..16384]=sim_batch (128,128)

    char* ws = (char*)d_ws;
    float2* pxl = (float2*)ws;                         ws += BB * CC * sizeof(float2);  // 512 KB
    float*  lg  = (float*)ws;                          ws += BB * CC * sizeof(float);   // 256 KB
    float*  lgT = (float*)ws;                          ws += CC * BB * sizeof(float);   // 256 KB
    float*  H   = (float*)ws;                          ws += BB * sizeof(float);
    float2* wxw = (float2*)ws;                         ws += BB * sizeof(float2);
    float*  lgw = (float*)ws;                          ws += BB * sizeof(float);
    int*    hits = (int*)ws;                           ws += BB * sizeof(int);
    double* partials = (double*)ws;                    ws += PAIRBLK * 4 * sizeof(double);
    unsigned int* ticket = (unsigned int*)ws;

    row_kernel<<<BB / 4, 256, 0, stream>>>(predicts, labels, T, pxl, lg, lgT, H,
                                           wxw, lgw, hits, ticket);
    main_kernel<<<GRID2, 256, 0, stream>>>(pxl, lg, lgT, H, wxw, lgw, labels,
                                           hits, sim_all, epoch, mu, eta,
                                           partials, ticket, out);
}

// Round 4
// 17.687 us; speedup vs baseline: 1.4212x; 1.4212x over previous
//
#include <hip/hip_runtime.h>

#define BB 512
#define CC 128
#define EPS 1e-6f
#define PAIRBLK 511   // 130816 pairs / 256 threads

__device__ __forceinline__ int tri(int a) { return (a * (1023 - a)) >> 1; }

// ---------------------------------------------------------------------------
// K1: 128 blocks x 256 threads; one wave per row, all-shuffle (no barriers).
//   pxl[b][c]  = (p, p*logp)
//   lg[b][c]   = log(p+eps)
//   rowdat[b]  = (H=sum_c p*logp, p[b,lb], p*logp[b,lb], lg[b,lb])
//   hits[b]    = runner-up class if top1==label else -1
// Also zeroes sim_batch (out+1): 128 blocks x 128 floats, coalesced.
// ---------------------------------------------------------------------------
__global__ __launch_bounds__(256) void row_kernel(
    const float* __restrict__ predicts, const int* __restrict__ labels,
    const float* __restrict__ Tp,
    float2* __restrict__ pxl, float* __restrict__ lg,
    float4* __restrict__ rowdat, int* __restrict__ hits,
    float* __restrict__ sim_batch) {
    const int tid = threadIdx.x, lane = tid & 63;
    const int row = blockIdx.x * 4 + (tid >> 6);

    if (tid < 128) sim_batch[blockIdx.x * 128 + tid] = 0.0f;

    const float T = Tp[0];
    const float z0 = predicts[row * CC + lane] / T;
    const float z1 = predicts[row * CC + 64 + lane] / T;

    float m = fmaxf(z0, z1);
    for (int s = 32; s; s >>= 1) m = fmaxf(m, __shfl_xor(m, s, 64));
    const float e0 = expf(z0 - m), e1 = expf(z1 - m);
    float sum = e0 + e1;
    for (int s = 32; s; s >>= 1) sum += __shfl_xor(sum, s, 64);

    const float inv = 1.0f / sum, ls = logf(sum);
    const float p0 = e0 * inv, p1 = e1 * inv;
    const float lp0 = (z0 - m) - ls, lp1 = (z1 - m) - ls;  // log p
    const float lg0 = logf(p0 + EPS), lg1 = logf(p1 + EPS);
    const float x0 = p0 * lp0, x1 = p1 * lp1;

    pxl[row * CC + lane]      = make_float2(p0, x0);
    pxl[row * CC + 64 + lane] = make_float2(p1, x1);
    lg[row * CC + lane]      = lg0;
    lg[row * CC + 64 + lane] = lg1;

    float hs = x0 + x1;  // butterfly -> all lanes hold total
    for (int s = 32; s; s >>= 1) hs += __shfl_xor(hs, s, 64);

    const int lbl = labels[row];
    if (lane == (lbl & 63)) {
        const bool hi = lbl >= 64;
        rowdat[row] = make_float4(hs, hi ? p1 : p0, hi ? x1 : x0, hi ? lg1 : lg0);
    }

    // stable top-2: key = (float bits << 32) | (127 - idx); p>=0 so bit order
    // == value order; ties -> larger (127-idx) -> smaller idx (argsort(-p)).
    unsigned long long k0 =
        (((unsigned long long)__float_as_uint(p0)) << 32) | (unsigned)(127 - lane);
    unsigned long long k1 =
        (((unsigned long long)__float_as_uint(p1)) << 32) | (unsigned)(127 - (lane + 64));
    unsigned long long hi = k0 > k1 ? k0 : k1;
    unsigned long long lo = k0 > k1 ? k1 : k0;
    for (int s = 32; s; s >>= 1) {
        const unsigned long long ohi = __shfl_xor(hi, s, 64);
        const unsigned long long olo = __shfl_xor(lo, s, 64);
        const unsigned long long nhi = hi > ohi ? hi : ohi;
        const unsigned long long c1 = hi > ohi ? ohi : hi;
        const unsigned long long c2 = lo > olo ? lo : olo;
        lo = c1 > c2 ? c1 : c2;
        hi = nhi;
    }
    if (lane == 0) {
        const int i1 = 127 - (int)(hi & 0xFFFFFFFFu);
        const int i2 = 127 - (int)(lo & 0xFFFFFFFFu);
        hits[row] = (i1 == lbl) ? i2 : -1;
    }
}

// ---------------------------------------------------------------------------
// K2: 511 blocks x 256 threads, one thread per pair (a<b). No fences/atomics.
// diff-label: 2-term closed form (1 scattered load, rest cache-local).
// same-label: cooperative wave dot via ballot + shuffle.
// Writes 4 double partials per block.
// ---------------------------------------------------------------------------
__global__ __launch_bounds__(256) void pairs_kernel(
    const float2* __restrict__ pxl, const float* __restrict__ lg,
    const float4* __restrict__ rowdat, const int* __restrict__ labels,
    const float* __restrict__ sim_all, const int* __restrict__ epoch_p,
    double* __restrict__ partials) {
    const int tid = threadIdx.x, lane = tid & 63, bid = blockIdx.x;
    const int k = bid * 256 + tid;  // 0..130815, all valid

    int a = (int)((1023.0 - sqrt(1046529.0 - 8.0 * (double)k)) * 0.5);
    if (a < 0) a = 0;
    while (tri(a + 1) <= k) ++a;
    while (tri(a) > k) --a;
    const int b = a + 1 + (k - tri(a));

    const int la = labels[a], lb = labels[b];
    const bool same = (la == lb);
    const float4 ra = rowdat[a];  // (H, w, xw, lgw) — a nearly block-uniform

    double ic = 0.0, isc = 0.0, scnt = 0.0, dcnt = 0.0;

    if (!same) {
        const float g = lg[b * CC + la];          // the one scattered load
        const float4 rb = rowdat[b];              // stride-16B over b
        const float2 pa = pxl[a * CC + lb];       // row-a local, L1
        const float t1 = ra.z - ra.y * g;         // xw[a] - w[a]*lg[b,la]
        const float t2 = pa.y - pa.x * rb.w;      // xlg[a,lb] - p[a,lb]*lgw[b]
        const float sim = (epoch_p[0] == 0) ? 1.0f : sim_all[la * CC + lb];
        isc = fabsf((t1 + t2) * sim);
        dcnt = 1.0;
    }

    // cooperative same-label dots: IC term = |H[a] - dot(p[a], lg[b])|
    unsigned long long msk = __ballot(same);
    while (msk) {
        const int src = __builtin_ctzll(msk);
        msk &= msk - 1;
        const int aa = __shfl(a, src, 64);
        const int bb = __shfl(b, src, 64);
        float dot = pxl[aa * CC + lane].x * lg[bb * CC + lane] +
                    pxl[aa * CC + 64 + lane].x * lg[bb * CC + 64 + lane];
        for (int s = 32; s; s >>= 1) dot += __shfl_xor(dot, s, 64);
        if (lane == src) { ic = fabs((double)ra.x - (double)dot); scnt = 1.0; }
    }

    __shared__ double sred[4][4];
    double vals[4] = {ic, isc, scnt, dcnt};
    #pragma unroll
    for (int q = 0; q < 4; ++q) {
        double v = vals[q];
        for (int s = 32; s; s >>= 1) v += __shfl_xor(v, s, 64);
        if (lane == 0) sred[tid >> 6][q] = v;
    }
    __syncthreads();
    if (tid < 4)
        partials[bid * 4 + tid] =
            sred[0][tid] + sred[1][tid] + sred[2][tid] + sred[3][tid];
}

// ---------------------------------------------------------------------------
// K3: one block. Reduce 511 partial rows -> out[0] with the reference's exact
// guard sequence; apply the <=512 sim_batch hit increments (zeroed by K1).
// ---------------------------------------------------------------------------
__global__ __launch_bounds__(256) void finalize_kernel(
    const double* __restrict__ partials, const int* __restrict__ labels,
    const int* __restrict__ hits, const float* __restrict__ mu_p,
    const float* __restrict__ eta_p, float* __restrict__ out) {
    const int tid = threadIdx.x, lane = tid & 63;

    float* sb = out + 1;
    for (int r = tid; r < BB; r += 256) {
        const int h = hits[r];
        if (h >= 0) atomicAdd(&sb[labels[r] * CC + h], 1.0f);
    }

    double v0 = 0, v1 = 0, v2 = 0, v3 = 0;
    for (int i = tid; i < PAIRBLK; i += 256) {
        v0 += partials[i * 4 + 0];
        v1 += partials[i * 4 + 1];
        v2 += partials[i * 4 + 2];
        v3 += partials[i * 4 + 3];
    }
    for (int s = 32; s; s >>= 1) {
        v0 += __shfl_xor(v0, s, 64);
        v1 += __shfl_xor(v1, s, 64);
        v2 += __shfl_xor(v2, s, 64);
        v3 += __shfl_xor(v3, s, 64);
    }
    __shared__ double sred[4][4];
    if (lane == 0) {
        sred[tid >> 6][0] = v0; sred[tid >> 6][1] = v1;
        sred[tid >> 6][2] = v2; sred[tid >> 6][3] = v3;
    }
    __syncthreads();
    if (tid == 0) {
        double IC  = sred[0][0] + sred[1][0] + sred[2][0] + sred[3][0];
        double ISC = sred[0][1] + sred[1][1] + sred[2][1] + sred[3][1];
        const double sc = sred[0][2] + sred[1][2] + sred[2][2] + sred[3][2];
        const double dc = sred[0][3] + sred[1][3] + sred[2][3] + sred[3][3];
        if (sc != 0.0) IC = IC / sc;
        if (dc != 0.0) ISC = ISC / dc;
        if (ISC != 0.0) ISC = (1.0 / (ISC + (double)EPS)) * (double)mu_p[0];
        IC = IC * (double)eta_p[0];
        out[0] = (float)(IC + ISC);
    }
}

extern "C" void kernel_launch(void* const* d_in, const int* in_sizes, int n_in,
                              void* d_out, int out_size, void* d_ws, size_t ws_size,
                              hipStream_t stream) {
    const float* predicts = (const float*)d_in[0];  // (512,128) f32
    const int*   labels   = (const int*)d_in[1];    // (512,) i32
    const float* sim_all  = (const float*)d_in[2];  // (128,128) f32
    const int*   epoch    = (const int*)d_in[3];    // scalar i32
    const float* T        = (const float*)d_in[4];  // scalar f32
    const float* mu       = (const float*)d_in[5];  // scalar f32
    const float* eta      = (const float*)d_in[6];  // scalar f32

    float* out = (float*)d_out;  // [0]=IC+ISC, [1..16384]=sim_batch (128,128)

    char* ws = (char*)d_ws;
    float2* pxl     = (float2*)ws;   ws += BB * CC * sizeof(float2);   // 512 KB
    float*  lg      = (float*)ws;    ws += BB * CC * sizeof(float);    // 256 KB
    float4* rowdat  = (float4*)ws;   ws += BB * sizeof(float4);
    int*    hits    = (int*)ws;      ws += BB * sizeof(int);
    double* partials = (double*)ws;  // 511*4 doubles, 8B-aligned

    row_kernel<<<BB / 4, 256, 0, stream>>>(predicts, labels, T, pxl, lg, rowdat,
                                           hits, out + 1);
    pairs_kernel<<<PAIRBLK, 256, 0, stream>>>(pxl, lg, rowdat, labels, sim_all,
                                              epoch, partials);
    finalize_kernel<<<1, 256, 0, stream>>>(partials, labels, hits, mu, eta, out);
}